// Round 6
// baseline (9819.270 us; speedup 1.0000x reference)
//
#include <hip/hip_runtime.h>

// Encoder: embed -> 4x input GEMM (bf16 MFMA, bias folded, gate-interleaved out)
//          -> 4x LSTM scan (SINGLE-WG recurrence: full Whh as i8 row-scaled
//             register-resident B-frags, h via LDS only — no inter-WG sync)
//          -> co-attention + output head.
// Sizes: V=100000 E=300 H=256 OUT=3 B=128 LS=128 LT=8

typedef unsigned short u16;
typedef unsigned long long u64;
typedef float f32x4 __attribute__((ext_vector_type(4)));
typedef int   i32x4 __attribute__((ext_vector_type(4)));
typedef short bf16x8 __attribute__((ext_vector_type(8)));
typedef short s16x4 __attribute__((ext_vector_type(4)));

#define KP 320   // E=300 padded to mult of 32
#define FH 1024  // 4*H
#define HH 256   // H

static __device__ __forceinline__ u16 f2bf(float f) {
    unsigned int u = __float_as_uint(f);
    u += 0x7FFFu + ((u >> 16) & 1u);          // RNE
    return (u16)(u >> 16);
}
static __device__ __forceinline__ float bf2f(u16 s) {
    return __uint_as_float((unsigned int)s << 16);
}
static __device__ __forceinline__ float sigm(float x) {
    return __builtin_amdgcn_rcpf(1.0f + __expf(-x));
}
static __device__ __forceinline__ float tanh_(float x) {
    return 1.0f - 2.0f * __builtin_amdgcn_rcpf(1.0f + __expf(2.0f * x));
}

// ---------------------------------------------------------------- embedding
__global__ void embed_kernel(const int* __restrict__ sen, const int* __restrict__ tgt,
                             const float* __restrict__ emb,
                             u16* __restrict__ Xs, u16* __restrict__ Xt)
{
    int row = blockIdx.x;
    int tok; u16* dst;
    if (row < 16384) { tok = sen[row]; dst = Xs + (size_t)row * KP; }
    else             { tok = tgt[row - 16384]; dst = Xt + (size_t)(row - 16384) * KP; }
    const float* src = emb + (size_t)tok * 300;
    for (int k = threadIdx.x; k < KP; k += blockDim.x) {
        float v = (k < 300 && tok != 0) ? src[k] : 0.0f;   // padding_idx=0
        dst[k] = f2bf(v);
    }
}

// ---------------------------------------------------------------- weight prep (one dir)
__global__ void prep_weights_kernel(const float* __restrict__ Wih,
                                    const float* __restrict__ bih, const float* __restrict__ bhh,
                                    u16* __restrict__ WihB, float* __restrict__ biasB)
{
    int idx = blockIdx.x * 256 + threadIdx.x;
    if (idx < FH * KP) {
        int row = idx / KP, k = idx - row * KP;
        WihB[idx] = (k < 300) ? f2bf(Wih[row * 300 + k]) : (u16)0;
    }
    if (idx < FH)      biasB[idx] = bih[idx] + bhh[idx];
}

// ---------------------------------------------------------------- Whh -> i8 row-scaled
// one wave per Whh row: rowmax -> q = rint(W*127/rowmax), dq = rowmax/127^2
__global__ __launch_bounds__(64) void whh_quant_kernel(
    const float* __restrict__ Whh, char* __restrict__ Wq, float* __restrict__ wdq)
{
    int row = blockIdx.x, tid = threadIdx.x;
    const float* src = Whh + (size_t)row * HH;
    float m = 0.0f;
    for (int k = tid; k < HH; k += 64) m = fmaxf(m, fabsf(src[k]));
    for (int off = 32; off; off >>= 1) m = fmaxf(m, __shfl_down(m, off));
    m = __shfl(m, 0);
    float qs = (m > 0.0f) ? 127.0f / m : 0.0f;
    for (int k = tid; k < HH; k += 64)
        Wq[(size_t)row * HH + k] = (char)(int)rintf(src[k] * qs);
    if (tid == 0) wdq[row] = (m > 0.0f) ? m / (127.0f * 127.0f) : 0.0f;
}

// ---------------------------------------------------------------- input GEMM
// G layout out: [row m][unit*4 + gate] bf16, bias folded in.
__global__ __launch_bounds__(256) void input_gemm_kernel(
    const u16* __restrict__ X, const u16* __restrict__ W,
    const float* __restrict__ bias, u16* __restrict__ G, int M)
{
    int wave = threadIdx.x >> 6, lane = threadIdx.x & 63;
    int r = lane & 15, quad = lane >> 4;
    int m0 = blockIdx.x * 64 + wave * 16;
    int n0 = blockIdx.y * 64;
    f32x4 acc[4] = {};
    const u16* xr = X + (size_t)(m0 + r) * KP + quad * 8;
    const u16* wr = W + (size_t)(n0 + r) * KP + quad * 8;
#pragma unroll
    for (int k0 = 0; k0 < KP; k0 += 32) {
        bf16x8 a = *(const bf16x8*)(xr + k0);
#pragma unroll
        for (int j = 0; j < 4; ++j) {
            bf16x8 b = *(const bf16x8*)(wr + (size_t)j * 16 * KP + k0);
            acc[j] = __builtin_amdgcn_mfma_f32_16x16x32_bf16(a, b, acc[j], 0, 0, 0);
        }
    }
#pragma unroll
    for (int j = 0; j < 4; ++j)
#pragma unroll
        for (int reg = 0; reg < 4; ++reg) {
            int row = quad * 4 + reg;
            int n = n0 + j * 16 + r;
            int gate = n >> 8, unit = n & 255;
            G[(size_t)(m0 + row) * FH + unit * 4 + gate] = f2bf(acc[j][reg] + bias[n]);
        }
}

// ---------------------------------------------------------------- LSTM scan
// 32 WGs x 512 thr: dir = bx>>3, batch chunk = (bx&7)*16. ONE WG holds the
// ENTIRE direction recurrence for its 16 batches: Whh (i8, row-scaled) lives
// in registers; h round-trips through LDS only. No inter-WG communication.
// REGISTER BUDGET (the R5 lesson): 8-wave WG => hard cap 256 VGPR/lane
// (2 waves/SIMD). launch_bounds(512,2) acted as min-2-BLOCKS/CU => 128-VGPR
// cap => the 128-VGPR Bq array spilled to scratch => 9.3ms. Budget here:
// Bq 128 + acc 32 + gv 32 + c/dqv 16 + a ~4 (loaded per-kt) + misc ~20 = ~232.
__global__ __launch_bounds__(512, 1) void lstm_scan_kernel(
    const char*  __restrict__ WqB,   // [4][1024][256] i8
    const float* __restrict__ wdq,   // [4][1024] dequant scales
    const u16*   __restrict__ Gs,    // [2][16384][1024] bf16 (gate-interleaved, bias folded)
    const u16*   __restrict__ Gt,    // [2][1024][1024] bf16
    float* __restrict__ senH,        // [128][128][512]
    float* __restrict__ tgtH)        // [128][8][512]
{
    const int bx  = blockIdx.x;
    const int dir = bx >> 3;
    const int b0  = (bx & 7) << 4;
    const int T   = (dir < 2) ? 128 : 8;
    const int rev = dir & 1;

    const char* Wq = WqB + (size_t)dir * FH * HH;
    const u16*  G  = (dir < 2) ? (Gs + (size_t)dir * 16384 * FH)
                               : (Gt + (size_t)(dir - 2) * 1024 * FH);
    float* Hout = (dir < 2) ? senH : tgtH;
    const int hofs = rev ? 256 : 0;

    const int tid  = threadIdx.x;
    const int w    = tid >> 6, lane = tid & 63;
    const int r    = lane & 15, quad = lane >> 4;

    __shared__ char  hb8[16][272];   // h as i8 (A-operand source)
    __shared__ float hbf[16][264];   // h as f32 (coalesced senH staging)

    // ---- Whh i8 B-frags into registers (persist across all steps)
    // Bq[tt][g][kt]: row = g*256 + w*32 + tt*16 + r, k-slice = kt*32 + quad*8
    u64 Bq[2][4][8];
    float dqv[2][4];
#pragma unroll
    for (int tt = 0; tt < 2; ++tt)
#pragma unroll
        for (int g = 0; g < 4; ++g) {
            int row = g * 256 + w * 32 + tt * 16 + r;
            dqv[tt][g] = wdq[dir * FH + row];
#pragma unroll
            for (int kt = 0; kt < 8; ++kt)
                Bq[tt][g][kt] = *(const u64*)(Wq + ((size_t)row << 8) + kt * 32 + quad * 8);
        }

    // ---- zero h(–1)
    for (int i = tid; i < 16 * 272; i += 512) (&hb8[0][0])[i] = 0;
    __syncthreads();

    const int u0 = w * 32 + r;          // this lane's unit (tt adds +16)
    float c[2][4] = {};                 // cell state [tt][reg]
    s16x4 gv[2][2][4];                  // pregates, double-buffered [buf][tt][reg]

    // preload G for s=0
    {
        int t0 = rev ? T - 1 : 0;
#pragma unroll
        for (int tt = 0; tt < 2; ++tt)
#pragma unroll
            for (int reg = 0; reg < 4; ++reg)
                gv[0][tt][reg] = *(const s16x4*)(G + ((size_t)(b0 + quad * 4 + reg) * T + t0) * FH
                                                 + (u0 + tt * 16) * 4);
    }

    int cur = 0, t_prev = 0;
    for (int s = 0; s < T; ++s) {
        const int t = rev ? (T - 1 - s) : s;

        // ---- trailing coalesced senH write of h(s-1) (reads hbf)
        if (s > 0) {
            int bb = tid >> 5, uu = (tid & 31) * 8;
            f32x4 v0 = *(const f32x4*)&hbf[bb][uu];
            f32x4 v1 = *(const f32x4*)&hbf[bb][uu + 4];
            float* dst = Hout + ((size_t)(b0 + bb) * T + t_prev) * 512 + hofs + uu;
            *(f32x4*)dst = v0; *(f32x4*)(dst + 4) = v1;
        }

        // ---- recurrent matmul: 64 i8 MFMAs; A-frag loaded per-kt (short live range)
        i32x4 acc[2][4] = {};
#pragma unroll
        for (int kt = 0; kt < 8; ++kt) {
            u64 a = *(const u64*)&hb8[r][quad * 8 + kt * 32];
#pragma unroll
            for (int tt = 0; tt < 2; ++tt)
#pragma unroll
                for (int g = 0; g < 4; ++g)
                    acc[tt][g] = __builtin_amdgcn_mfma_i32_16x16x32_i8(
                        (long long)a, (long long)Bq[tt][g][kt], acc[tt][g], 0, 0, 0);
        }

        // ---- prefetch pregates for s+1 (independent of h)
        if (s + 1 < T) {
            int tn = rev ? (T - 2 - s) : (s + 1);
#pragma unroll
            for (int tt = 0; tt < 2; ++tt)
#pragma unroll
                for (int reg = 0; reg < 4; ++reg)
                    gv[cur ^ 1][tt][reg] = *(const s16x4*)(G + ((size_t)(b0 + quad * 4 + reg) * T + tn) * FH
                                                           + (u0 + tt * 16) * 4);
        }

        __syncthreads();   // all reads of h(s-1) (MFMA A-frags + hbf flush) done

        // ---- gates -> c,h ; h to LDS (i8 + f32)
#pragma unroll
        for (int tt = 0; tt < 2; ++tt)
#pragma unroll
            for (int reg = 0; reg < 4; ++reg) {
                int bb = quad * 4 + reg;
                float pi = (float)acc[tt][0][reg] * dqv[tt][0] + bf2f((u16)gv[cur][tt][reg].x);
                float pf = (float)acc[tt][1][reg] * dqv[tt][1] + bf2f((u16)gv[cur][tt][reg].y);
                float pg = (float)acc[tt][2][reg] * dqv[tt][2] + bf2f((u16)gv[cur][tt][reg].z);
                float po = (float)acc[tt][3][reg] * dqv[tt][3] + bf2f((u16)gv[cur][tt][reg].w);
                float ig = sigm(pi), fg = sigm(pf), gg = tanh_(pg), og = sigm(po);
                float cn = fg * c[tt][reg] + ig * gg;
                c[tt][reg] = cn;
                float hn = og * tanh_(cn);
                int u = u0 + tt * 16;
                hb8[bb][u] = (char)(int)rintf(hn * 127.0f);
                hbf[bb][u] = hn;
            }
        __syncthreads();   // h(s) visible
        cur ^= 1;
        t_prev = t;
    }

    // ---- flush senH for the final step
    {
        int bb = tid >> 5, uu = (tid & 31) * 8;
        f32x4 v0 = *(const f32x4*)&hbf[bb][uu];
        f32x4 v1 = *(const f32x4*)&hbf[bb][uu + 4];
        float* dst = Hout + ((size_t)(b0 + bb) * T + t_prev) * 512 + hofs + uu;
        *(f32x4*)dst = v0; *(f32x4*)(dst + 4) = v1;
    }
}

// ---------------------------------------------------------------- attention + head
__global__ __launch_bounds__(256) void attn_out_kernel(
    const float* __restrict__ senH, const float* __restrict__ tgtH,
    const float* __restrict__ Wout, const float* __restrict__ bout,
    float* __restrict__ out)
{
    int b = blockIdx.x, tid = threadIdx.x;
    __shared__ float tg[8][512];
    __shared__ float Am[128][9];
    __shared__ float rowm[128][9];
    __shared__ float mcol[8], csum[8], rvec[8], attn[128], score[512], lg[3];

    const float* tgg = tgtH + (size_t)b * 8 * 512;
    for (int i = tid; i < 4096; i += 256) tg[i >> 9][i & 511] = tgg[i];
    __syncthreads();

    {   // A[s][t] = sen_h[b,s,:] . tgt_h[b,t,:]
        int s = tid >> 1, t0 = (tid & 1) * 4;
        const float* sr = senH + ((size_t)b * 128 + s) * 512;
        float d0 = 0, d1 = 0, d2 = 0, d3 = 0;
        for (int h = 0; h < 512; ++h) {
            float x = sr[h];
            d0 += x * tg[t0 + 0][h]; d1 += x * tg[t0 + 1][h];
            d2 += x * tg[t0 + 2][h]; d3 += x * tg[t0 + 3][h];
        }
        Am[s][t0 + 0] = d0; Am[s][t0 + 1] = d1; Am[s][t0 + 2] = d2; Am[s][t0 + 3] = d3;
    }
    __syncthreads();

    if (tid < 8) {  // col-softmax stats over s, per t
        float m = -1e30f;
        for (int s = 0; s < 128; ++s) m = fmaxf(m, Am[s][tid]);
        float sum = 0;
        for (int s = 0; s < 128; ++s) sum += __expf(Am[s][tid] - m);
        mcol[tid] = m; csum[tid] = sum;
    }
    if (tid >= 64 && tid < 192) {  // row softmax per s
        int s = tid - 64;
        float m = -1e30f;
        for (int t = 0; t < 8; ++t) m = fmaxf(m, Am[s][t]);
        float e[8], sum = 0;
        for (int t = 0; t < 8; ++t) { e[t] = __expf(Am[s][t] - m); sum += e[t]; }
        float inv = __builtin_amdgcn_rcpf(sum);
        for (int t = 0; t < 8; ++t) rowm[s][t] = e[t] * inv;
    }
    __syncthreads();
    if (tid < 8) {
        float sum = 0;
        for (int s = 0; s < 128; ++s) sum += rowm[s][tid];
        rvec[tid] = sum * (1.0f / 128.0f);
    }
    __syncthreads();
    if (tid < 128) {
        float a = 0;
        for (int t = 0; t < 8; ++t)
            a += __expf(Am[tid][t] - mcol[t]) / csum[t] * rvec[t];
        attn[tid] = a;
    }
    __syncthreads();
    for (int h = tid; h < 512; h += 256) {
        float acc = 0;
        const float* sp = senH + (size_t)b * 128 * 512 + h;
        for (int s = 0; s < 128; ++s) acc += attn[s] * sp[(size_t)s * 512];
        score[h] = acc;
    }
    __syncthreads();
    if (tid < 3) {
        float acc = bout[tid];
        const float* wr = Wout + tid * 512;
        for (int h = 0; h < 512; ++h) acc += score[h] * wr[h];
        lg[tid] = acc;
    }
    __syncthreads();
    if (tid == 0) {
        float m = fmaxf(lg[0], fmaxf(lg[1], lg[2]));
        float e0 = __expf(lg[0] - m), e1 = __expf(lg[1] - m), e2 = __expf(lg[2] - m);
        float inv = 1.0f / (e0 + e1 + e2);
        out[b * 3 + 0] = e0 * inv; out[b * 3 + 1] = e1 * inv; out[b * 3 + 2] = e2 * inv;
    }
}

// ---------------------------------------------------------------- launch
extern "C" void kernel_launch(void* const* d_in, const int* in_sizes, int n_in,
                              void* d_out, int out_size, void* d_ws, size_t ws_size,
                              hipStream_t stream)
{
    const int*   sen = (const int*)d_in[0];
    const int*   tgt = (const int*)d_in[1];
    const float* emb = (const float*)d_in[2];
    const float* Wih[4] = {(const float*)d_in[3],  (const float*)d_in[7],
                           (const float*)d_in[11], (const float*)d_in[15]};
    const float* Whh[4] = {(const float*)d_in[4],  (const float*)d_in[8],
                           (const float*)d_in[12], (const float*)d_in[16]};
    const float* bih[4] = {(const float*)d_in[5],  (const float*)d_in[9],
                           (const float*)d_in[13], (const float*)d_in[17]};
    const float* bhh[4] = {(const float*)d_in[6],  (const float*)d_in[10],
                           (const float*)d_in[14], (const float*)d_in[18]};
    const float* Wout = (const float*)d_in[19];
    const float* bout = (const float*)d_in[20];
    float* out = (float*)d_out;

    char* ws = (char*)d_ws;
    size_t off = 0;
    auto alloc = [&](size_t bytes) -> void* {
        void* p = ws + off; off += (bytes + 255) & ~(size_t)255; return p;
    };
    u16*   Xs    = (u16*)alloc((size_t)16384 * KP * 2);
    u16*   Xt    = (u16*)alloc((size_t)1024 * KP * 2);
    u16*   WihB  = (u16*)alloc((size_t)4 * FH * KP * 2);
    char*  WqB   = (char*)alloc((size_t)4 * FH * HH);
    float* wdq   = (float*)alloc((size_t)4 * FH * 4);
    float* biasB = (float*)alloc((size_t)4 * FH * 4);
    u16*   Gs    = (u16*)alloc((size_t)2 * 16384 * FH * 2);
    u16*   Gt    = (u16*)alloc((size_t)2 * 1024 * FH * 2);
    float* senH  = (float*)alloc((size_t)128 * 128 * 512 * 4);
    float* tgtH  = (float*)alloc((size_t)128 * 8 * 512 * 4);
    (void)ws_size; (void)in_sizes; (void)n_in; (void)out_size;

    embed_kernel<<<17408, 128, 0, stream>>>(sen, tgt, emb, Xs, Xt);
    for (int d = 0; d < 4; ++d) {
        prep_weights_kernel<<<1280, 256, 0, stream>>>(
            Wih[d], bih[d], bhh[d],
            WihB + (size_t)d * FH * KP, biasB + (size_t)d * FH);
        whh_quant_kernel<<<FH, 64, 0, stream>>>(
            Whh[d], WqB + (size_t)d * FH * HH, wdq + (size_t)d * FH);
    }

    dim3 gsen(256, 16), gtgt(16, 16);
    input_gemm_kernel<<<gsen, 256, 0, stream>>>(Xs, WihB + (size_t)0 * FH * KP,
                                                biasB + 0 * FH, Gs, 16384);
    input_gemm_kernel<<<gsen, 256, 0, stream>>>(Xs, WihB + (size_t)1 * FH * KP,
                                                biasB + 1 * FH, Gs + (size_t)16384 * FH, 16384);
    input_gemm_kernel<<<gtgt, 256, 0, stream>>>(Xt, WihB + (size_t)2 * FH * KP,
                                                biasB + 2 * FH, Gt, 1024);
    input_gemm_kernel<<<gtgt, 256, 0, stream>>>(Xt, WihB + (size_t)3 * FH * KP,
                                                biasB + 3 * FH, Gt + (size_t)1024 * FH, 1024);

    lstm_scan_kernel<<<32, 512, 0, stream>>>(WqB, wdq, Gs, Gt, senH, tgtH);
    attn_out_kernel<<<128, 256, 0, stream>>>(senH, tgtH, Wout, bout, out);
}

// Round 7
// 953.673 us; speedup vs baseline: 10.2963x; 10.2963x over previous
//
#include <hip/hip_runtime.h>

// Encoder: embed -> 4x input GEMM (bf16 MFMA, bias folded, gate-interleaved out)
//          -> 4x LSTM scan (SINGLE-WG recurrence, 256-thr WG: full Whh as i8
//             row-scaled register-resident B-frags @ 1 wave/SIMD, h via LDS)
//          -> co-attention + output head.
// Sizes: V=100000 E=300 H=256 OUT=3 B=128 LS=128 LT=8

typedef unsigned short u16;
typedef unsigned long long u64;
typedef float f32x4 __attribute__((ext_vector_type(4)));
typedef int   i32x4 __attribute__((ext_vector_type(4)));
typedef short bf16x8 __attribute__((ext_vector_type(8)));
typedef short s16x4 __attribute__((ext_vector_type(4)));

#define KP 320   // E=300 padded to mult of 32
#define FH 1024  // 4*H
#define HH 256   // H

static __device__ __forceinline__ u16 f2bf(float f) {
    unsigned int u = __float_as_uint(f);
    u += 0x7FFFu + ((u >> 16) & 1u);          // RNE
    return (u16)(u >> 16);
}
static __device__ __forceinline__ float bf2f(u16 s) {
    return __uint_as_float((unsigned int)s << 16);
}
static __device__ __forceinline__ float sigm(float x) {
    return __builtin_amdgcn_rcpf(1.0f + __expf(-x));
}
static __device__ __forceinline__ float tanh_(float x) {
    return 1.0f - 2.0f * __builtin_amdgcn_rcpf(1.0f + __expf(2.0f * x));
}

// ---------------------------------------------------------------- embedding
__global__ void embed_kernel(const int* __restrict__ sen, const int* __restrict__ tgt,
                             const float* __restrict__ emb,
                             u16* __restrict__ Xs, u16* __restrict__ Xt)
{
    int row = blockIdx.x;
    int tok; u16* dst;
    if (row < 16384) { tok = sen[row]; dst = Xs + (size_t)row * KP; }
    else             { tok = tgt[row - 16384]; dst = Xt + (size_t)(row - 16384) * KP; }
    const float* src = emb + (size_t)tok * 300;
    for (int k = threadIdx.x; k < KP; k += blockDim.x) {
        float v = (k < 300 && tok != 0) ? src[k] : 0.0f;   // padding_idx=0
        dst[k] = f2bf(v);
    }
}

// ---------------------------------------------------------------- weight prep (one dir)
__global__ void prep_weights_kernel(const float* __restrict__ Wih,
                                    const float* __restrict__ bih, const float* __restrict__ bhh,
                                    u16* __restrict__ WihB, float* __restrict__ biasB)
{
    int idx = blockIdx.x * 256 + threadIdx.x;
    if (idx < FH * KP) {
        int row = idx / KP, k = idx - row * KP;
        WihB[idx] = (k < 300) ? f2bf(Wih[row * 300 + k]) : (u16)0;
    }
    if (idx < FH)      biasB[idx] = bih[idx] + bhh[idx];
}

// ---------------------------------------------------------------- Whh -> i8 row-scaled
__global__ __launch_bounds__(64) void whh_quant_kernel(
    const float* __restrict__ Whh, char* __restrict__ Wq, float* __restrict__ wdq)
{
    int row = blockIdx.x, tid = threadIdx.x;
    const float* src = Whh + (size_t)row * HH;
    float m = 0.0f;
    for (int k = tid; k < HH; k += 64) m = fmaxf(m, fabsf(src[k]));
    for (int off = 32; off; off >>= 1) m = fmaxf(m, __shfl_down(m, off));
    m = __shfl(m, 0);
    float qs = (m > 0.0f) ? 127.0f / m : 0.0f;
    for (int k = tid; k < HH; k += 64)
        Wq[(size_t)row * HH + k] = (char)(int)rintf(src[k] * qs);
    if (tid == 0) wdq[row] = (m > 0.0f) ? m / (127.0f * 127.0f) : 0.0f;
}

// ---------------------------------------------------------------- input GEMM
// G layout out: [row m][unit*4 + gate] bf16, bias folded in.
__global__ __launch_bounds__(256) void input_gemm_kernel(
    const u16* __restrict__ X, const u16* __restrict__ W,
    const float* __restrict__ bias, u16* __restrict__ G, int M)
{
    int wave = threadIdx.x >> 6, lane = threadIdx.x & 63;
    int r = lane & 15, quad = lane >> 4;
    int m0 = blockIdx.x * 64 + wave * 16;
    int n0 = blockIdx.y * 64;
    f32x4 acc[4] = {};
    const u16* xr = X + (size_t)(m0 + r) * KP + quad * 8;
    const u16* wr = W + (size_t)(n0 + r) * KP + quad * 8;
#pragma unroll
    for (int k0 = 0; k0 < KP; k0 += 32) {
        bf16x8 a = *(const bf16x8*)(xr + k0);
#pragma unroll
        for (int j = 0; j < 4; ++j) {
            bf16x8 b = *(const bf16x8*)(wr + (size_t)j * 16 * KP + k0);
            acc[j] = __builtin_amdgcn_mfma_f32_16x16x32_bf16(a, b, acc[j], 0, 0, 0);
        }
    }
#pragma unroll
    for (int j = 0; j < 4; ++j)
#pragma unroll
        for (int reg = 0; reg < 4; ++reg) {
            int row = quad * 4 + reg;
            int n = n0 + j * 16 + r;
            int gate = n >> 8, unit = n & 255;
            G[(size_t)(m0 + row) * FH + unit * 4 + gate] = f2bf(acc[j][reg] + bias[n]);
        }
}

// ---------------------------------------------------------------- LSTM scan
// 32 WGs x 256 thr (4 waves): dir = bx>>3, batch chunk = (bx&7)*16. ONE WG
// holds the entire direction recurrence for its 16 batches. Wave w owns units
// [w*64,w*64+64) x 4 gates = 256 Whh rows: Bq[4][4][8] u64 = 256 VGPR/lane of
// i8 B-frags. 4-wave WG @ launch_bounds(256,1) => 1 wave/SIMD => 512-VGPR cap
// (R3 verified pressure-driven allocation works in this regime; R5/R6's
// 8-wave WG was clamped to 128 => full spill => 9.4ms). All register arrays
// statically indexed (R6's gv[cur] dynamic indexing forced scratch).
// mfma_i32_16x16x32_i8: A lane(m=l&15,k=quad*8+j), B lane(n=l&15,k=quad*8+j),
// D lane(col=l&15,row=quad*4+reg) — all 4 gates of a unit land in one lane.
__global__ __launch_bounds__(256, 1) void lstm_scan_kernel(
    const char*  __restrict__ WqB,   // [4][1024][256] i8
    const float* __restrict__ wdq,   // [4][1024] dequant scales
    const u16*   __restrict__ Gs,    // [2][16384][1024] bf16 (gate-interleaved, bias folded)
    const u16*   __restrict__ Gt,    // [2][1024][1024] bf16
    float* __restrict__ senH,        // [128][128][512]
    float* __restrict__ tgtH)        // [128][8][512]
{
    const int bx  = blockIdx.x;
    const int dir = bx >> 3;
    const int b0  = (bx & 7) << 4;
    const int T   = (dir < 2) ? 128 : 8;
    const int rev = dir & 1;

    const char* Wq = WqB + (size_t)dir * FH * HH;
    const u16*  G  = (dir < 2) ? (Gs + (size_t)dir * 16384 * FH)
                               : (Gt + (size_t)(dir - 2) * 1024 * FH);
    float* Hout = (dir < 2) ? senH : tgtH;
    const int hofs = rev ? 256 : 0;

    const int tid  = threadIdx.x;
    const int w    = tid >> 6, lane = tid & 63;
    const int r    = lane & 15, quad = lane >> 4;

    __shared__ char  hb8[16][272];   // h as i8 (A-operand source)
    __shared__ float hbf[16][264];   // h as f32 (coalesced Hout staging)

    // ---- Whh i8 B-frags into registers (persist across all steps)
    // Bq[j][g][kt]: row = g*256 + w*64 + j*16 + r, k-slice = kt*32 + quad*8
    u64 Bq[4][4][8];
    float dqv[4][4];
#pragma unroll
    for (int j = 0; j < 4; ++j)
#pragma unroll
        for (int g = 0; g < 4; ++g) {
            int row = g * 256 + w * 64 + j * 16 + r;
            dqv[j][g] = wdq[dir * FH + row];
#pragma unroll
            for (int kt = 0; kt < 8; ++kt)
                Bq[j][g][kt] = *(const u64*)(Wq + ((size_t)row << 8) + kt * 32 + quad * 8);
        }

    // ---- zero h(-1)
    for (int i = tid; i < 16 * 272; i += 256) (&hb8[0][0])[i] = 0;
    __syncthreads();

    float c[4][4] = {};   // cell state [j][reg]
    int t_prev = 0;

    for (int s = 0; s < T; ++s) {
        const int t = rev ? (T - 1 - s) : s;

        // ---- pregates for this step (independent of h; latency hides under MFMA)
        s16x4 gv[4][4];
#pragma unroll
        for (int j = 0; j < 4; ++j)
#pragma unroll
            for (int reg = 0; reg < 4; ++reg)
                gv[j][reg] = *(const s16x4*)(G + ((size_t)(b0 + quad * 4 + reg) * T + t) * FH
                                             + (w * 64 + j * 16 + r) * 4);

        // ---- trailing coalesced Hout write of h(s-1) (reads hbf)
        if (s > 0) {
            int bb = tid >> 4, uu = (tid & 15) * 16;
            float* dst = Hout + ((size_t)(b0 + bb) * T + t_prev) * 512 + hofs + uu;
#pragma unroll
            for (int q = 0; q < 4; ++q)
                *(f32x4*)(dst + q * 4) = *(const f32x4*)&hbf[bb][uu + q * 4];
        }

        // ---- recurrent matmul: 128 i8 MFMAs/wave
        i32x4 acc[4][4] = {};   // [j][g]
#pragma unroll
        for (int kt = 0; kt < 8; ++kt) {
            u64 a = *(const u64*)&hb8[r][quad * 8 + kt * 32];
#pragma unroll
            for (int j = 0; j < 4; ++j)
#pragma unroll
                for (int g = 0; g < 4; ++g)
                    acc[j][g] = __builtin_amdgcn_mfma_i32_16x16x32_i8(
                        (long long)a, (long long)Bq[j][g][kt], acc[j][g], 0, 0, 0);
        }
        __syncthreads();   // all reads of h(s-1) (ds A-frags + hbf flush) done

        // ---- gates -> c,h ; h to LDS (i8 + f32)
#pragma unroll
        for (int j = 0; j < 4; ++j)
#pragma unroll
            for (int reg = 0; reg < 4; ++reg) {
                int bb = quad * 4 + reg;
                float pi = (float)acc[j][0][reg] * dqv[j][0] + bf2f((u16)gv[j][reg].x);
                float pf = (float)acc[j][1][reg] * dqv[j][1] + bf2f((u16)gv[j][reg].y);
                float pg = (float)acc[j][2][reg] * dqv[j][2] + bf2f((u16)gv[j][reg].z);
                float po = (float)acc[j][3][reg] * dqv[j][3] + bf2f((u16)gv[j][reg].w);
                float ig = sigm(pi), fg = sigm(pf), gg = tanh_(pg), og = sigm(po);
                float cn = fg * c[j][reg] + ig * gg;
                c[j][reg] = cn;
                float hn = og * tanh_(cn);
                int u = w * 64 + j * 16 + r;
                hb8[bb][u] = (char)(int)rintf(hn * 127.0f);
                hbf[bb][u] = hn;
            }
        __syncthreads();   // h(s) visible
        t_prev = t;
    }

    // ---- flush Hout for the final step
    {
        int bb = tid >> 4, uu = (tid & 15) * 16;
        float* dst = Hout + ((size_t)(b0 + bb) * T + t_prev) * 512 + hofs + uu;
#pragma unroll
        for (int q = 0; q < 4; ++q)
            *(f32x4*)(dst + q * 4) = *(const f32x4*)&hbf[bb][uu + q * 4];
    }
}

// ---------------------------------------------------------------- attention + head
__global__ __launch_bounds__(256) void attn_out_kernel(
    const float* __restrict__ senH, const float* __restrict__ tgtH,
    const float* __restrict__ Wout, const float* __restrict__ bout,
    float* __restrict__ out)
{
    int b = blockIdx.x, tid = threadIdx.x;
    __shared__ float tg[8][512];
    __shared__ float Am[128][9];
    __shared__ float rowm[128][9];
    __shared__ float mcol[8], csum[8], rvec[8], attn[128], score[512], lg[3];

    const float* tgg = tgtH + (size_t)b * 8 * 512;
    for (int i = tid; i < 4096; i += 256) tg[i >> 9][i & 511] = tgg[i];
    __syncthreads();

    {   // A[s][t] = sen_h[b,s,:] . tgt_h[b,t,:]
        int s = tid >> 1, t0 = (tid & 1) * 4;
        const float* sr = senH + ((size_t)b * 128 + s) * 512;
        float d0 = 0, d1 = 0, d2 = 0, d3 = 0;
        for (int h = 0; h < 512; ++h) {
            float x = sr[h];
            d0 += x * tg[t0 + 0][h]; d1 += x * tg[t0 + 1][h];
            d2 += x * tg[t0 + 2][h]; d3 += x * tg[t0 + 3][h];
        }
        Am[s][t0 + 0] = d0; Am[s][t0 + 1] = d1; Am[s][t0 + 2] = d2; Am[s][t0 + 3] = d3;
    }
    __syncthreads();

    if (tid < 8) {  // col-softmax stats over s, per t
        float m = -1e30f;
        for (int s = 0; s < 128; ++s) m = fmaxf(m, Am[s][tid]);
        float sum = 0;
        for (int s = 0; s < 128; ++s) sum += __expf(Am[s][tid] - m);
        mcol[tid] = m; csum[tid] = sum;
    }
    if (tid >= 64 && tid < 192) {  // row softmax per s
        int s = tid - 64;
        float m = -1e30f;
        for (int t = 0; t < 8; ++t) m = fmaxf(m, Am[s][t]);
        float e[8], sum = 0;
        for (int t = 0; t < 8; ++t) { e[t] = __expf(Am[s][t] - m); sum += e[t]; }
        float inv = __builtin_amdgcn_rcpf(sum);
        for (int t = 0; t < 8; ++t) rowm[s][t] = e[t] * inv;
    }
    __syncthreads();
    if (tid < 8) {
        float sum = 0;
        for (int s = 0; s < 128; ++s) sum += rowm[s][tid];
        rvec[tid] = sum * (1.0f / 128.0f);
    }
    __syncthreads();
    if (tid < 128) {
        float a = 0;
        for (int t = 0; t < 8; ++t)
            a += __expf(Am[tid][t] - mcol[t]) / csum[t] * rvec[t];
        attn[tid] = a;
    }
    __syncthreads();
    for (int h = tid; h < 512; h += 256) {
        float acc = 0;
        const float* sp = senH + (size_t)b * 128 * 512 + h;
        for (int s = 0; s < 128; ++s) acc += attn[s] * sp[(size_t)s * 512];
        score[h] = acc;
    }
    __syncthreads();
    if (tid < 3) {
        float acc = bout[tid];
        const float* wr = Wout + tid * 512;
        for (int h = 0; h < 512; ++h) acc += score[h] * wr[h];
        lg[tid] = acc;
    }
    __syncthreads();
    if (tid == 0) {
        float m = fmaxf(lg[0], fmaxf(lg[1], lg[2]));
        float e0 = __expf(lg[0] - m), e1 = __expf(lg[1] - m), e2 = __expf(lg[2] - m);
        float inv = 1.0f / (e0 + e1 + e2);
        out[b * 3 + 0] = e0 * inv; out[b * 3 + 1] = e1 * inv; out[b * 3 + 2] = e2 * inv;
    }
}

// ---------------------------------------------------------------- launch
extern "C" void kernel_launch(void* const* d_in, const int* in_sizes, int n_in,
                              void* d_out, int out_size, void* d_ws, size_t ws_size,
                              hipStream_t stream)
{
    const int*   sen = (const int*)d_in[0];
    const int*   tgt = (const int*)d_in[1];
    const float* emb = (const float*)d_in[2];
    const float* Wih[4] = {(const float*)d_in[3],  (const float*)d_in[7],
                           (const float*)d_in[11], (const float*)d_in[15]};
    const float* Whh[4] = {(const float*)d_in[4],  (const float*)d_in[8],
                           (const float*)d_in[12], (const float*)d_in[16]};
    const float* bih[4] = {(const float*)d_in[5],  (const float*)d_in[9],
                           (const float*)d_in[13], (const float*)d_in[17]};
    const float* bhh[4] = {(const float*)d_in[6],  (const float*)d_in[10],
                           (const float*)d_in[14], (const float*)d_in[18]};
    const float* Wout = (const float*)d_in[19];
    const float* bout = (const float*)d_in[20];
    float* out = (float*)d_out;

    char* ws = (char*)d_ws;
    size_t off = 0;
    auto alloc = [&](size_t bytes) -> void* {
        void* p = ws + off; off += (bytes + 255) & ~(size_t)255; return p;
    };
    u16*   Xs    = (u16*)alloc((size_t)16384 * KP * 2);
    u16*   Xt    = (u16*)alloc((size_t)1024 * KP * 2);
    u16*   WihB  = (u16*)alloc((size_t)4 * FH * KP * 2);
    char*  WqB   = (char*)alloc((size_t)4 * FH * HH);
    float* wdq   = (float*)alloc((size_t)4 * FH * 4);
    float* biasB = (float*)alloc((size_t)4 * FH * 4);
    u16*   Gs    = (u16*)alloc((size_t)2 * 16384 * FH * 2);
    u16*   Gt    = (u16*)alloc((size_t)2 * 1024 * FH * 2);
    float* senH  = (float*)alloc((size_t)128 * 128 * 512 * 4);
    float* tgtH  = (float*)alloc((size_t)128 * 8 * 512 * 4);
    (void)ws_size; (void)in_sizes; (void)n_in; (void)out_size;

    embed_kernel<<<17408, 128, 0, stream>>>(sen, tgt, emb, Xs, Xt);
    for (int d = 0; d < 4; ++d) {
        prep_weights_kernel<<<1280, 256, 0, stream>>>(
            Wih[d], bih[d], bhh[d],
            WihB + (size_t)d * FH * KP, biasB + (size_t)d * FH);
        whh_quant_kernel<<<FH, 64, 0, stream>>>(
            Whh[d], WqB + (size_t)d * FH * HH, wdq + (size_t)d * FH);
    }

    dim3 gsen(256, 16), gtgt(16, 16);
    input_gemm_kernel<<<gsen, 256, 0, stream>>>(Xs, WihB + (size_t)0 * FH * KP,
                                                biasB + 0 * FH, Gs, 16384);
    input_gemm_kernel<<<gsen, 256, 0, stream>>>(Xs, WihB + (size_t)1 * FH * KP,
                                                biasB + 1 * FH, Gs + (size_t)16384 * FH, 16384);
    input_gemm_kernel<<<gtgt, 256, 0, stream>>>(Xt, WihB + (size_t)2 * FH * KP,
                                                biasB + 2 * FH, Gt, 1024);
    input_gemm_kernel<<<gtgt, 256, 0, stream>>>(Xt, WihB + (size_t)3 * FH * KP,
                                                biasB + 3 * FH, Gt + (size_t)1024 * FH, 1024);

    lstm_scan_kernel<<<32, 256, 0, stream>>>(WqB, wdq, Gs, Gt, senH, tgtH);
    attn_out_kernel<<<128, 256, 0, stream>>>(senH, tgtH, Wout, bout, out);
}